// Round 2
// baseline (315.743 us; speedup 1.0000x reference)
//
#include <hip/hip_runtime.h>

// AvgPoolVectorsPerWSI: x [2048, 512, 7, 7] f32, idx [2048] i32 in [0,64)
// out [64, 512, 1, 1] f32 = segment_mean over samples of spatial-sum / 49.

#define N_SAMPLES 2048
#define M_CHANNELS 512
#define SPATIAL 49              // 7*7
#define GROUPS 64

// One block per sample, 128 threads. Thread t reads 49 contiguous float4s
// (= 196 floats = exactly channels 4t..4t+3), accumulates 4 channel sums in
// registers, then scatter-adds into the [64][512] accumulator.
__global__ __launch_bounds__(128) void spatial_scatter_kernel(
    const float* __restrict__ x, const int* __restrict__ idx,
    float* __restrict__ accum) {
  const int n = blockIdx.x;
  const int t = threadIdx.x;
  const int g = idx[n];  // wave-uniform scalar load

  // Per-sample base: 25088 floats = 6272 float4 (16B aligned).
  const float4* p = reinterpret_cast<const float4*>(x)
                    + (size_t)n * (M_CHANNELS * SPATIAL / 4)
                    + (size_t)t * SPATIAL;

  float s0 = 0.f, s1 = 0.f, s2 = 0.f, s3 = 0.f;
#pragma unroll
  for (int j = 0; j < SPATIAL; ++j) {
    const float4 v = p[j];
#pragma unroll
    for (int k = 0; k < 4; ++k) {
      const int e = 4 * j + k;       // local element 0..195
      const int c = e / SPATIAL;     // compile-time constant channel 0..3
      const float val = (k == 0) ? v.x : (k == 1) ? v.y : (k == 2) ? v.z : v.w;
      if (c == 0) s0 += val;
      else if (c == 1) s1 += val;
      else if (c == 2) s2 += val;
      else s3 += val;
    }
  }

  float* a = accum + (size_t)g * M_CHANNELS + 4 * t;
  atomicAdd(a + 0, s0);
  atomicAdd(a + 1, s1);
  atomicAdd(a + 2, s2);
  atomicAdd(a + 3, s3);
}

// One block per group g, 512 threads (one per channel). Recompute the group
// count from idx (tiny, L2-hot), then scale the accumulated sum in place.
__global__ __launch_bounds__(512) void finalize_kernel(
    const int* __restrict__ idx, float* __restrict__ out) {
  const int g = blockIdx.x;
  const int t = threadIdx.x;

  __shared__ int cnt;
  if (t == 0) cnt = 0;
  __syncthreads();

  int local = 0;
#pragma unroll
  for (int i = 0; i < N_SAMPLES / 512; ++i)
    local += (idx[t + i * 512] == g) ? 1 : 0;
  atomicAdd(&cnt, local);
  __syncthreads();

  // count==0 -> inv=inf, 0*inf=NaN, matching reference 0/0.
  const float inv = 1.0f / ((float)cnt * (float)SPATIAL);
  out[(size_t)g * M_CHANNELS + t] *= inv;
}

extern "C" void kernel_launch(void* const* d_in, const int* in_sizes, int n_in,
                              void* d_out, int out_size, void* d_ws, size_t ws_size,
                              hipStream_t stream) {
  const float* x = (const float*)d_in[0];
  const int* idx = (const int*)d_in[1];
  float* out = (float*)d_out;

  // Zero the accumulator (harness poisons d_out with 0xAA each call).
  hipMemsetAsync(out, 0, (size_t)GROUPS * M_CHANNELS * sizeof(float), stream);

  spatial_scatter_kernel<<<N_SAMPLES, 128, 0, stream>>>(x, idx, out);
  finalize_kernel<<<GROUPS, M_CHANNELS, 0, stream>>>(idx, out);
}

// Round 3
// 278.988 us; speedup vs baseline: 1.1317x; 1.1317x over previous
//
#include <hip/hip_runtime.h>

// AvgPoolVectorsPerWSI: x [2048, 512, 7, 7] f32, idx [2048] i32 in [0,64)
// out [64, 512, 1, 1] f32 = segment_mean over samples of spatial-sum / 49.

#define N_SAMPLES 2048
#define M_CHANNELS 512
#define SPATIAL 49                      // 7*7
#define GROUPS 64
#define SAMPLE_FLOATS (M_CHANNELS * SPATIAL)   // 25088 floats = 100352 B
#define HALF_FLOATS (SAMPLE_FLOATS / 2)        // 12544 floats = 50176 B
#define HALF_F4 (HALF_FLOATS / 4)              // 3136 float4

typedef __attribute__((address_space(1))) const void global_void;
typedef __attribute__((address_space(3))) void lds_void;

// One block per (sample, half): 256 threads stage 50 KB into LDS via
// global_load_lds (width 16, perfectly coalesced: 1 KiB per wave-instr),
// then thread t sums channel (h*256+t)'s 49 consecutive floats from LDS
// (stride-49 reads are bank-conflict-free: 49 odd, 17 coprime to 32),
// then one atomicAdd per channel into the [64][512] accumulator.
// LDS = 50176 B -> 3 blocks/CU resident -> stage/reduce overlap across blocks.
__global__ __launch_bounds__(256) void scatter_kernel(
    const float* __restrict__ x, const int* __restrict__ idx,
    float* __restrict__ accum) {
  __shared__ float lds[HALF_FLOATS];
  const int blk = blockIdx.x;
  const int n = blk >> 1;        // sample
  const int h = blk & 1;         // half: channels [h*256, h*256+256)
  const int t = threadIdx.x;
  const int wave = t >> 6;
  const int lane = t & 63;
  const int g = idx[n];          // wave-uniform scalar load

  const float* src = x + (size_t)n * SAMPLE_FLOATS + (size_t)h * HALF_FLOATS;

  // 3136 float4s = 12 rounds x 256 threads + 64 by wave 0.
  // LDS dest is wave-uniform base; HW adds lane*16. Global src is per-lane.
#pragma unroll
  for (int k = 0; k < 12; ++k) {
    const int base_f4 = k * 256 + wave * 64;        // wave-uniform
    __builtin_amdgcn_global_load_lds(
        (global_void*)(src + (size_t)(base_f4 + lane) * 4),
        (lds_void*)(lds + (size_t)base_f4 * 4), 16, 0, 0);
  }
  if (wave == 0) {
    const int base_f4 = 12 * 256;
    __builtin_amdgcn_global_load_lds(
        (global_void*)(src + (size_t)(base_f4 + lane) * 4),
        (lds_void*)(lds + (size_t)base_f4 * 4), 16, 0, 0);
  }
  __syncthreads();  // compiler drains vmcnt(0) before s_barrier

  // Channel reduce: thread t owns local channel t (49 consecutive floats).
  const float* row = lds + t * SPATIAL;
  float s = 0.f;
#pragma unroll
  for (int i = 0; i < SPATIAL; ++i) s += row[i];

  atomicAdd(accum + (size_t)g * M_CHANNELS + h * 256 + t, s);
}

// One block per group g, 512 threads (one per channel). Recompute the group
// count from idx (tiny, L2-hot), then scale the accumulated sum in place.
__global__ __launch_bounds__(512) void finalize_kernel(
    const int* __restrict__ idx, float* __restrict__ out) {
  const int g = blockIdx.x;
  const int t = threadIdx.x;

  __shared__ int cnt;
  if (t == 0) cnt = 0;
  __syncthreads();

  int local = 0;
#pragma unroll
  for (int i = 0; i < N_SAMPLES / 512; ++i)
    local += (idx[t + i * 512] == g) ? 1 : 0;
  atomicAdd(&cnt, local);
  __syncthreads();

  // count==0 -> inv=inf, 0*inf=NaN, matching reference 0/0.
  const float inv = 1.0f / ((float)cnt * (float)SPATIAL);
  out[(size_t)g * M_CHANNELS + t] *= inv;
}

extern "C" void kernel_launch(void* const* d_in, const int* in_sizes, int n_in,
                              void* d_out, int out_size, void* d_ws, size_t ws_size,
                              hipStream_t stream) {
  const float* x = (const float*)d_in[0];
  const int* idx = (const int*)d_in[1];
  float* out = (float*)d_out;

  // Zero the accumulator (harness poisons d_out with 0xAA each call).
  hipMemsetAsync(out, 0, (size_t)GROUPS * M_CHANNELS * sizeof(float), stream);

  scatter_kernel<<<N_SAMPLES * 2, 256, 0, stream>>>(x, idx, out);
  finalize_kernel<<<GROUPS, M_CHANNELS, 0, stream>>>(idx, out);
}

// Round 4
// 278.526 us; speedup vs baseline: 1.1336x; 1.0017x over previous
//
#include <hip/hip_runtime.h>

// AvgPoolVectorsPerWSI: x [2048, 512, 7, 7] f32, idx [2048] i32 in [0,64)
// out [64, 512, 1, 1] f32 = segment_mean over samples of spatial-sum / 49.

#define N_SAMPLES 2048
#define M_CHANNELS 512
#define SPATIAL 49                            // 7*7
#define GROUPS 64
#define SAMPLE_FLOATS (M_CHANNELS * SPATIAL)  // 25088 floats = 100352 B
#define WAVE_CH 64                            // channels per wave (1/lane)
#define WAVE_FLOATS (WAVE_CH * SPATIAL)       // 3136 floats = 12544 B
// per-wave staging: 784 float4 = 12 full 64-lane rounds + 16-lane tail

typedef __attribute__((address_space(1))) const void global_void;
typedef __attribute__((address_space(3))) void lds_void;

// One block per (sample, half) = 256 threads = 4 waves; each wave owns 64
// channels and a PRIVATE 12544-B LDS region. Wave-local pipeline:
//   13x global_load_lds (1 KiB each, perfectly coalesced)
//   -> s_waitcnt vmcnt(0) (wave-local, NO block barrier)
//   -> 49 stride-49 ds_read_b32 per thread (17 coprime 32 -> 2 lanes/bank,
//      conflict-free) -> 1 atomicAdd per channel.
// 3 blocks/CU (50 KB LDS) x 4 waves = 12 independent pipelines per CU.
__global__ __launch_bounds__(256) void scatter_kernel(
    const float* __restrict__ x, const int* __restrict__ idx,
    float* __restrict__ accum) {
  __shared__ float lds[4 * WAVE_FLOATS];
  const int blk = blockIdx.x;
  const int n = blk >> 1;        // sample
  const int h = blk & 1;         // half: channels [h*256, h*256+256)
  const int t = threadIdx.x;
  const int w = t >> 6;          // wave 0..3
  const int lane = t & 63;
  const int g = idx[n];          // wave-uniform scalar load

  const float* src = x + (size_t)n * SAMPLE_FLOATS
                       + (size_t)h * (SAMPLE_FLOATS / 2)
                       + (size_t)w * WAVE_FLOATS;
  float* ldsw = lds + w * WAVE_FLOATS;  // wave-private region

  // Stage 784 float4: LDS dest is wave-uniform base (+ lane*16 in HW).
#pragma unroll
  for (int k = 0; k < 12; ++k) {
    __builtin_amdgcn_global_load_lds(
        (global_void*)(src + (size_t)(k * 64 + lane) * 4),
        (lds_void*)(ldsw + k * 256), 16, 0, 0);
  }
  if (lane < 16) {  // tail: 16 float4
    __builtin_amdgcn_global_load_lds(
        (global_void*)(src + (size_t)(768 + lane) * 4),
        (lds_void*)(ldsw + 3072), 16, 0, 0);
  }

  // Wave-local drain; no __syncthreads. sched_barrier keeps ds_read below
  // the waitcnt (rule #18: hipcc can hoist past inline-asm waitcnt).
  asm volatile("s_waitcnt vmcnt(0)" ::: "memory");
  __builtin_amdgcn_sched_barrier(0);

  // Thread's channel row: 49 consecutive floats at lane*49.
  const float* row = ldsw + lane * SPATIAL;
  float s = 0.f;
#pragma unroll
  for (int i = 0; i < SPATIAL; ++i) s += row[i];

  atomicAdd(accum + (size_t)g * M_CHANNELS + h * (M_CHANNELS / 2)
                  + w * WAVE_CH + lane, s);
}

// One block per group g, 512 threads (one per channel). Recompute the group
// count from idx (tiny, L2-hot), then scale the accumulated sum in place.
__global__ __launch_bounds__(512) void finalize_kernel(
    const int* __restrict__ idx, float* __restrict__ out) {
  const int g = blockIdx.x;
  const int t = threadIdx.x;

  __shared__ int cnt;
  if (t == 0) cnt = 0;
  __syncthreads();

  int local = 0;
#pragma unroll
  for (int i = 0; i < N_SAMPLES / 512; ++i)
    local += (idx[t + i * 512] == g) ? 1 : 0;
  atomicAdd(&cnt, local);
  __syncthreads();

  // count==0 -> inv=inf, 0*inf=NaN, matching reference 0/0.
  const float inv = 1.0f / ((float)cnt * (float)SPATIAL);
  out[(size_t)g * M_CHANNELS + t] *= inv;
}

extern "C" void kernel_launch(void* const* d_in, const int* in_sizes, int n_in,
                              void* d_out, int out_size, void* d_ws, size_t ws_size,
                              hipStream_t stream) {
  const float* x = (const float*)d_in[0];
  const int* idx = (const int*)d_in[1];
  float* out = (float*)d_out;

  // Zero the accumulator (harness poisons d_out with 0xAA each call).
  hipMemsetAsync(out, 0, (size_t)GROUPS * M_CHANNELS * sizeof(float), stream);

  scatter_kernel<<<N_SAMPLES * 2, 256, 0, stream>>>(x, idx, out);
  finalize_kernel<<<GROUPS, M_CHANNELS, 0, stream>>>(idx, out);
}